// Round 10
// baseline (185.506 us; speedup 1.0000x reference)
//
#include <hip/hip_runtime.h>
#include <hip/hip_bf16.h>

// N=524288, D=9, E=2, H=128, M=32, O=2, K=1.
// CONFIRMED (R9 pass): d_in fp32, d_out fp32 (N*2 + loss), ref = plain fp32
// numpy on raw inputs; comparison happens in bf16-cast space (absmax came out
// 1 bf16-ulp). Gates are one-hot 1.0 (K=1 softmax); loss from expert counts.
// R10: expert-partitioned compute (wave-uniform expert -> s_load weights,
// 12 VALU/j instead of 24), anti-remat barrier after x load, finalize fused
// via last-block ticket, parallel prep detect. Numerics identical to R9.
#define NTOK 524288
#define TPB  256
#define NBLK (NTOK / TPB)   // 2048

__device__ __forceinline__ float bf2f(unsigned short u) {
    union { unsigned int i; float f; } v;
    v.i = ((unsigned int)u) << 16;
    return v.f;
}

__device__ __forceinline__ float ldq(const void* p, int i, bool f32) {
    if (f32) return ((const float*)p)[i];
    return bf2f(((const unsigned short*)p)[i]);   // safety fallback
}

// ---------------------------------------------------------------------------
// Prep (1 block): parallel dtype detect, zero counters, stage w_gate + folded
// biases, pack weights expert-major for wave-uniform s_load:
//   wpack[e*1536 + j*12 + {0..8: W1[e][:,j], 9: b1[e][j], 10,11: (W2@Wout)[e][j][:]}]
//   bpp[e*2+o] = b2[e]@Wout[:,o] + bout[o]
// ---------------------------------------------------------------------------
__global__ void prep_kernel(const void* __restrict__ num_prop,
                            const void* __restrict__ wgate,
                            const void* __restrict__ W1,
                            const void* __restrict__ b1,
                            const void* __restrict__ W2,
                            const void* __restrict__ b2,
                            const void* __restrict__ Wout,
                            const void* __restrict__ bout,
                            unsigned int* __restrict__ cnt1,
                            unsigned int* __restrict__ done,
                            int* __restrict__ flag,
                            float* __restrict__ bpp,
                            float* __restrict__ wgf,
                            float* __restrict__ wpack)
{
    __shared__ int sbad;
    const int t = threadIdx.x;
    if (t == 0) { sbad = 0; *cnt1 = 0u; *done = 0u; }
    __syncthreads();
    if (t < 72) {   // parallel detect: bf16 N(0,1) exponents cluster near 127
        unsigned short u = ((const unsigned short*)num_prop)[t];
        int e = (u >> 7) & 0xFF;
        if (e < 64 || e > 191) sbad = 1;   // benign race: all writers store 1
    }
    __syncthreads();
    const bool f32 = (sbad != 0);
    if (t == 0) *flag = sbad;

    if (t < 18) wgf[t] = ldq(wgate, t, f32);

    if (t < 4) {  // bpp[e][o] = sum_m b2[e][m]*Wout[m][o] + bout[o]
        int e = t >> 1, o = t & 1;
        float acc = ldq(bout, o, f32);
        for (int m = 0; m < 32; ++m)
            acc += ldq(b2, e * 32 + m, f32) * ldq(Wout, m * 2 + o, f32);
        bpp[t] = acc;
    }

    const int e = t >> 7;       // 256 threads -> (e, j)
    const int j = t & 127;
    float p0 = 0.f, p1 = 0.f;
    for (int m = 0; m < 32; ++m) {
        float w = ldq(W2, (e * 128 + j) * 32 + m, f32);
        p0 += w * ldq(Wout, m * 2 + 0, f32);
        p1 += w * ldq(Wout, m * 2 + 1, f32);
    }
    float* dst = wpack + e * 1536 + j * 12;
    #pragma unroll
    for (int d = 0; d < 9; ++d)
        dst[d] = ldq(W1, (e * 9 + d) * 128 + j, f32);
    dst[9]  = ldq(b1, e * 128 + j, f32);
    dst[10] = p0;
    dst[11] = p1;
}

// ---------------------------------------------------------------------------
// Main: gate -> block-level expert partition (prefix sums) -> each wave runs
// a wave-uniform expert (s_load weights, 12 VALU/j); boundary wave falls back
// to dense-both. Last-done block computes the loss (ticket + device fence).
// ---------------------------------------------------------------------------
__global__ __launch_bounds__(TPB, 6)
void moe_main(const void* __restrict__ xg,
              const int* __restrict__ flag,
              const float* __restrict__ wgf,
              const float* __restrict__ bpp,
              const float* __restrict__ wpack,
              unsigned int* __restrict__ cnt1,
              unsigned int* __restrict__ done,
              float2* __restrict__ out,
              float* __restrict__ loss_out)
{
    __shared__ float xs[TPB * 9];
    __shared__ unsigned short perm[TPB];
    __shared__ int wcnt[4];
    const int tid  = threadIdx.x;
    const int lane = tid & 63;
    const int wave = tid >> 6;

    // stage own token's x (36B/thread, semi-coalesced) + write to LDS for the
    // post-partition permuted read
    const bool f32 = (*flag) != 0;
    const int base = blockIdx.x * (TPB * 9);
    float xo[9];
    if (f32) {
        const float* xf = (const float*)xg + base + tid * 9;
        #pragma unroll
        for (int d = 0; d < 9; ++d) xo[d] = xf[d];
    } else {
        const unsigned short* xu = (const unsigned short*)xg + base + tid * 9;
        #pragma unroll
        for (int d = 0; d < 9; ++d) xo[d] = bf2f(xu[d]);
    }
    #pragma unroll
    for (int d = 0; d < 9; ++d) xs[tid * 9 + d] = xo[d];

    // gating: fp32 fma dot, argmax (tie -> expert 0, stable top_k)
    float l0 = 0.f, l1 = 0.f;
    #pragma unroll
    for (int d = 0; d < 9; ++d) {
        l0 = fmaf(xo[d], wgf[d * 2 + 0], l0);
        l1 = fmaf(xo[d], wgf[d * 2 + 1], l1);
    }
    const bool e1 = l1 > l0;

    // partition: e0 tokens -> [0, c0), e1 tokens -> [c0, 256)
    unsigned long long m1 = __ballot(e1);
    int pre1 = __builtin_amdgcn_mbcnt_hi((unsigned)(m1 >> 32),
               __builtin_amdgcn_mbcnt_lo((unsigned)m1, 0u));
    if (lane == 0) wcnt[wave] = (int)__popcll(m1);
    __syncthreads();
    int w0 = wcnt[0], w1 = wcnt[1], w2 = wcnt[2], w3 = wcnt[3];
    int c1_tot = w0 + w1 + w2 + w3;
    int c0_tot = TPB - c1_tot;
    int off1 = (wave > 0 ? w0 : 0) + (wave > 1 ? w1 : 0) + (wave > 2 ? w2 : 0);
    int off0 = wave * 64 - off1;
    int pos = e1 ? (c0_tot + off1 + pre1) : (off0 + (lane - pre1));
    perm[pos] = (unsigned short)tid;
    if (tid == 0) atomicAdd(cnt1, (unsigned int)c1_tot);
    __syncthreads();

    // permuted x load into registers
    const int tok = perm[tid];
    float x[9];
    #pragma unroll
    for (int d = 0; d < 9; ++d) x[d] = xs[tok * 9 + d];
    __syncthreads();   // LDS fence: forces x to stay in VGPRs (no remat)

    const bool my1 = (tid >= c0_tot);
    unsigned long long bm = __ballot(my1);

    float o0, o1;
    if (bm == 0ull || bm == ~0ull) {
        // wave-uniform expert: single-expert loop, 12 VALU/j, s_load weights
        const int eb = (bm != 0ull) ? 1 : 0;
        const float* wp = wpack + eb * 1536;
        float a0 = bpp[eb * 2 + 0], a1 = bpp[eb * 2 + 1];
        #pragma unroll 4
        for (int j = 0; j < 128; ++j) {
            const float* w = wp + j * 12;
            float h = w[9];
            #pragma unroll
            for (int d = 0; d < 9; ++d) h = fmaf(x[d], w[d], h);
            h = fmaxf(h, 0.f);
            a0 = fmaf(h, w[10], a0);
            a1 = fmaf(h, w[11], a1);
        }
        o0 = a0; o1 = a1;
    } else {
        // boundary wave: dense both experts, per-lane select (same math/order)
        float a00 = bpp[0], a01 = bpp[1], a10 = bpp[2], a11 = bpp[3];
        #pragma unroll 4
        for (int j = 0; j < 128; ++j) {
            const float* w0p = wpack + j * 12;
            const float* w1p = wpack + 1536 + j * 12;
            float h0 = w0p[9], h1 = w1p[9];
            #pragma unroll
            for (int d = 0; d < 9; ++d) {
                h0 = fmaf(x[d], w0p[d], h0);
                h1 = fmaf(x[d], w1p[d], h1);
            }
            h0 = fmaxf(h0, 0.f);
            h1 = fmaxf(h1, 0.f);
            a00 = fmaf(h0, w0p[10], a00);
            a01 = fmaf(h0, w0p[11], a01);
            a10 = fmaf(h1, w1p[10], a10);
            a11 = fmaf(h1, w1p[11], a11);
        }
        o0 = my1 ? a10 : a00;
        o1 = my1 ? a11 : a01;
    }

    float2 o; o.x = o0; o.y = o1;
    out[blockIdx.x * TPB + tok] = o;   // scattered within 2KB window

    // fused loss: last block to finish computes it.
    // gates one-hot 1.0 -> importance == load == counts; cv^2 ddof=1:
    // var=(c0-c1)^2/2, mean=N/2; loss = 0.01*2*cv^2.
    if (tid == 0) {
        __threadfence();
        unsigned int ticket = atomicAdd(done, 1u);
        if (ticket == (unsigned int)(NBLK - 1)) {
            double c1 = (double)atomicAdd(cnt1, 0u);
            double c0 = (double)NTOK - c1;
            double diff = c0 - c1;
            double mean = (double)NTOK * 0.5;
            double cv2  = (0.5 * diff * diff) / (mean * mean + 1e-10);
            *loss_out = (float)(0.02 * cv2);
        }
    }
}

extern "C" void kernel_launch(void* const* d_in, const int* in_sizes, int n_in,
                              void* d_out, int out_size, void* d_ws, size_t ws_size,
                              hipStream_t stream) {
    const void* num_prop = d_in[0]; // [N,9] fp32
    // d_in[1] = cat_prop (unused)
    const void* w_gate   = d_in[2]; // [9,2]
    const void* W1       = d_in[3]; // [2,9,128]
    const void* b1       = d_in[4]; // [2,128]
    const void* W2       = d_in[5]; // [2,128,32]
    const void* b2       = d_in[6]; // [2,32]
    const void* Wout     = d_in[7]; // [32,2]
    const void* bout     = d_in[8]; // [2]
    // d_in[9] = k (==1)

    char* ws = (char*)d_ws;
    unsigned int* cnt1 = (unsigned int*)ws;          // @0
    unsigned int* done = (unsigned int*)(ws + 4);    // @4
    int* flag          = (int*)(ws + 8);             // @8
    float* bpp         = (float*)(ws + 32);          // 4 f
    float* wgf         = (float*)(ws + 64);          // 18 f
    float* wpack       = (float*)(ws + 192);         // 3072 f (expert-major)

    float*  outf = (float*)d_out;                    // fp32: N*2 + loss
    float2* out2 = (float2*)d_out;

    hipLaunchKernelGGL(prep_kernel, dim3(1), dim3(256), 0, stream,
                       num_prop, w_gate, W1, b1, W2, b2, Wout, bout,
                       cnt1, done, flag, bpp, wgf, wpack);
    hipLaunchKernelGGL(moe_main, dim3(NBLK), dim3(TPB), 0, stream,
                       num_prop, flag, wgf, bpp, wpack, cnt1, done,
                       out2, outf + (size_t)NTOK * 2);
}

// Round 11
// 169.550 us; speedup vs baseline: 1.0941x; 1.0941x over previous
//
#include <hip/hip_runtime.h>
#include <hip/hip_bf16.h>

// N=524288, D=9, E=2, H=128, M=32, O=2, K=1.
// CONFIRMED: d_in fp32, d_out fp32 (N*2 + loss), ref = plain fp32 numpy on
// raw inputs; compare in bf16-cast space. Gates one-hot 1.0; loss from counts.
// R11: x loaded GLOBAL->REGISTERS directly (no LDS x array at all). R9/R10
// evidence: any LDS-resident x gets rematerialized inside the j-loop
// (VGPR_Count 12/16), making the kernel LDS-pipe-bound (~2300 ds_read/wave).
// Dense-both-experts j-loop (wave-uniform s_load weights), coalesced store.
// Fused loss via last-block ticket; parallel prep detect. 2 graph nodes.
#define NTOK 524288
#define TPB  256
#define NBLK (NTOK / TPB)   // 2048

__device__ __forceinline__ float bf2f(unsigned short u) {
    union { unsigned int i; float f; } v;
    v.i = ((unsigned int)u) << 16;
    return v.f;
}

__device__ __forceinline__ float ldq(const void* p, int i, bool f32) {
    if (f32) return ((const float*)p)[i];
    return bf2f(((const unsigned short*)p)[i]);   // safety fallback
}

// ---------------------------------------------------------------------------
// Prep (1 block): parallel dtype detect, zero counters, stage w_gate + folded
// biases, pack weights interleaved per hidden unit j (R9 layout):
//   wpack[j*24 + e*12 + {0..8: W1[e][:,j], 9: b1[e][j], 10,11: (W2@Wout)[e][j]}]
//   bpp[e*2+o] = b2[e]@Wout[:,o] + bout[o]
// ---------------------------------------------------------------------------
__global__ void prep_kernel(const void* __restrict__ num_prop,
                            const void* __restrict__ wgate,
                            const void* __restrict__ W1,
                            const void* __restrict__ b1,
                            const void* __restrict__ W2,
                            const void* __restrict__ b2,
                            const void* __restrict__ Wout,
                            const void* __restrict__ bout,
                            unsigned int* __restrict__ cnt1,
                            unsigned int* __restrict__ done,
                            int* __restrict__ flag,
                            float* __restrict__ bpp,
                            float* __restrict__ wgf,
                            float* __restrict__ wpack)
{
    __shared__ int sbad;
    const int t = threadIdx.x;
    if (t == 0) { sbad = 0; *cnt1 = 0u; *done = 0u; }
    __syncthreads();
    if (t < 72) {   // parallel detect: bf16 N(0,1) exponents cluster near 127
        unsigned short u = ((const unsigned short*)num_prop)[t];
        int e = (u >> 7) & 0xFF;
        if (e < 64 || e > 191) sbad = 1;   // benign race: all writers store 1
    }
    __syncthreads();
    const bool f32 = (sbad != 0);
    if (t == 0) *flag = sbad;

    if (t < 18) wgf[t] = ldq(wgate, t, f32);

    if (t < 4) {  // bpp[e][o] = sum_m b2[e][m]*Wout[m][o] + bout[o]
        int e = t >> 1, o = t & 1;
        float acc = ldq(bout, o, f32);
        for (int m = 0; m < 32; ++m)
            acc += ldq(b2, e * 32 + m, f32) * ldq(Wout, m * 2 + o, f32);
        bpp[t] = acc;
    }

    const int e = t >> 7;       // 256 threads -> (e, j)
    const int j = t & 127;
    float p0 = 0.f, p1 = 0.f;
    for (int m = 0; m < 32; ++m) {
        float w = ldq(W2, (e * 128 + j) * 32 + m, f32);
        p0 += w * ldq(Wout, m * 2 + 0, f32);
        p1 += w * ldq(Wout, m * 2 + 1, f32);
    }
    float* dst = wpack + j * 24 + e * 12;
    #pragma unroll
    for (int d = 0; d < 9; ++d)
        dst[d] = ldq(W1, (e * 9 + d) * 128 + j, f32);
    dst[9]  = ldq(b1, e * 128 + j, f32);
    dst[10] = p0;
    dst[11] = p1;
}

// ---------------------------------------------------------------------------
// Main: one thread per token, x in REGISTERS (direct global loads, no LDS x).
// Dense-both experts, wave-uniform weight indices -> s_load. Coalesced
// float2 store. Expert-1 count via ballot; loss by last-finished block.
// ---------------------------------------------------------------------------
__global__ __launch_bounds__(TPB, 6)
void moe_main(const void* __restrict__ xg,
              const int* __restrict__ flag,
              const float* __restrict__ wgf,
              const float* __restrict__ bpp,
              const float* __restrict__ wpack,
              unsigned int* __restrict__ cnt1,
              unsigned int* __restrict__ done,
              float2* __restrict__ out,
              float* __restrict__ loss_out)
{
    __shared__ unsigned int cblk;
    const int tid = threadIdx.x;
    if (tid == 0) cblk = 0u;
    __syncthreads();

    // x: global -> registers, stride-9 per lane (HBM at 3% -> slack is free)
    const bool f32 = (*flag) != 0;
    const int base = blockIdx.x * (TPB * 9) + tid * 9;
    float x[9];
    if (f32) {
        const float* xf = (const float*)xg + base;
        #pragma unroll
        for (int d = 0; d < 9; ++d) x[d] = xf[d];
    } else {
        const unsigned short* xu = (const unsigned short*)xg + base;
        #pragma unroll
        for (int d = 0; d < 9; ++d) x[d] = bf2f(xu[d]);
    }

    // gating: fp32 fma dot, argmax (tie -> expert 0, stable top_k)
    float l0 = 0.f, l1 = 0.f;
    #pragma unroll
    for (int d = 0; d < 9; ++d) {
        l0 = fmaf(x[d], wgf[d * 2 + 0], l0);
        l1 = fmaf(x[d], wgf[d * 2 + 1], l1);
    }
    const bool e1 = l1 > l0;

    unsigned long long bal = __ballot(e1);
    if ((tid & 63) == 0)
        atomicAdd(&cblk, (unsigned int)__popcll(bal));

    // accumulators pre-seeded with folded bias per expert
    float a00 = bpp[0], a01 = bpp[1], a10 = bpp[2], a11 = bpp[3];

    #pragma unroll 4
    for (int j = 0; j < 128; ++j) {
        const float* wp = wpack + j * 24;   // uniform index -> s_load
        float h0 = wp[9], h1 = wp[21];
        #pragma unroll
        for (int d = 0; d < 9; ++d) {
            h0 = fmaf(x[d], wp[d],      h0);
            h1 = fmaf(x[d], wp[12 + d], h1);
        }
        h0 = fmaxf(h0, 0.f);
        h1 = fmaxf(h1, 0.f);
        a00 = fmaf(h0, wp[10], a00);
        a01 = fmaf(h0, wp[11], a01);
        a10 = fmaf(h1, wp[22], a10);
        a11 = fmaf(h1, wp[23], a11);
    }

    float2 o;
    o.x = e1 ? a10 : a00;
    o.y = e1 ? a11 : a01;
    out[blockIdx.x * TPB + tid] = o;   // coalesced 8B/lane

    // block count -> global; last-finished block computes the loss.
    __syncthreads();
    if (tid == 0) {
        atomicAdd(cnt1, cblk);
        __threadfence();
        unsigned int ticket = atomicAdd(done, 1u);
        if (ticket == (unsigned int)(NBLK - 1)) {
            // gates one-hot 1.0 -> importance == load == counts; cv^2 ddof=1:
            // var=(c0-c1)^2/2, mean=N/2; loss = 0.01*2*cv^2 (~1e-9).
            double c1 = (double)atomicAdd(cnt1, 0u);
            double c0 = (double)NTOK - c1;
            double diff = c0 - c1;
            double mean = (double)NTOK * 0.5;
            double cv2  = (0.5 * diff * diff) / (mean * mean + 1e-10);
            *loss_out = (float)(0.02 * cv2);
        }
    }
}

extern "C" void kernel_launch(void* const* d_in, const int* in_sizes, int n_in,
                              void* d_out, int out_size, void* d_ws, size_t ws_size,
                              hipStream_t stream) {
    const void* num_prop = d_in[0]; // [N,9] fp32
    // d_in[1] = cat_prop (unused)
    const void* w_gate   = d_in[2]; // [9,2]
    const void* W1       = d_in[3]; // [2,9,128]
    const void* b1       = d_in[4]; // [2,128]
    const void* W2       = d_in[5]; // [2,128,32]
    const void* b2       = d_in[6]; // [2,32]
    const void* Wout     = d_in[7]; // [32,2]
    const void* bout     = d_in[8]; // [2]
    // d_in[9] = k (==1)

    char* ws = (char*)d_ws;
    unsigned int* cnt1 = (unsigned int*)ws;          // @0
    unsigned int* done = (unsigned int*)(ws + 4);    // @4
    int* flag          = (int*)(ws + 8);             // @8
    float* bpp         = (float*)(ws + 32);          // 4 f
    float* wgf         = (float*)(ws + 64);          // 18 f
    float* wpack       = (float*)(ws + 192);         // 3072 f (interleaved)

    float*  outf = (float*)d_out;                    // fp32: N*2 + loss
    float2* out2 = (float2*)d_out;

    hipLaunchKernelGGL(prep_kernel, dim3(1), dim3(256), 0, stream,
                       num_prop, w_gate, W1, b1, W2, b2, Wout, bout,
                       cnt1, done, flag, bpp, wgf, wpack);
    hipLaunchKernelGGL(moe_main, dim3(NBLK), dim3(TPB), 0, stream,
                       num_prop, flag, wgf, bpp, wpack, cnt1, done,
                       out2, outf + (size_t)NTOK * 2);
}

// Round 12
// 168.409 us; speedup vs baseline: 1.1015x; 1.0068x over previous
//
#include <hip/hip_runtime.h>
#include <hip/hip_bf16.h>

// N=524288, D=9, E=2, H=128, M=32, O=2, K=1.
// CONFIRMED: d_in fp32, d_out fp32 (N*2 + loss), ref = plain fp32 numpy on
// raw inputs; compare in bf16-cast space. Gates one-hot 1.0; loss from counts.
// R12: R11 + asm-pin of x[] into VGPRs. Evidence chain: R9 VGPR=12 (x remat
// from LDS, ds_read-bound, 57us); R11 VGPR=20 (x remat from GLOBAL -- legal
// under __restrict__ -- VMEM-bound, 85us, VALUBusy 47%). Empty inline asm
// "+v" makes x's definition opaque => must stay in VGPRs. launch_bounds
// (256,8): cap 64 VGPR (need ~40), full 32-wave/CU occupancy.
#define NTOK 524288
#define TPB  256
#define NBLK (NTOK / TPB)   // 2048

__device__ __forceinline__ float bf2f(unsigned short u) {
    union { unsigned int i; float f; } v;
    v.i = ((unsigned int)u) << 16;
    return v.f;
}

__device__ __forceinline__ float ldq(const void* p, int i, bool f32) {
    if (f32) return ((const float*)p)[i];
    return bf2f(((const unsigned short*)p)[i]);   // safety fallback
}

// ---------------------------------------------------------------------------
// Prep (1 block): parallel dtype detect, zero counters, stage w_gate + folded
// biases, pack weights interleaved per hidden unit j:
//   wpack[j*24 + e*12 + {0..8: W1[e][:,j], 9: b1[e][j], 10,11: (W2@Wout)[e][j]}]
//   bpp[e*2+o] = b2[e]@Wout[:,o] + bout[o]
// ---------------------------------------------------------------------------
__global__ void prep_kernel(const void* __restrict__ num_prop,
                            const void* __restrict__ wgate,
                            const void* __restrict__ W1,
                            const void* __restrict__ b1,
                            const void* __restrict__ W2,
                            const void* __restrict__ b2,
                            const void* __restrict__ Wout,
                            const void* __restrict__ bout,
                            unsigned int* __restrict__ cnt1,
                            unsigned int* __restrict__ done,
                            int* __restrict__ flag,
                            float* __restrict__ bpp,
                            float* __restrict__ wgf,
                            float* __restrict__ wpack)
{
    __shared__ int sbad;
    const int t = threadIdx.x;
    if (t == 0) { sbad = 0; *cnt1 = 0u; *done = 0u; }
    __syncthreads();
    if (t < 72) {   // parallel detect: bf16 N(0,1) exponents cluster near 127
        unsigned short u = ((const unsigned short*)num_prop)[t];
        int e = (u >> 7) & 0xFF;
        if (e < 64 || e > 191) sbad = 1;   // benign race: all writers store 1
    }
    __syncthreads();
    const bool f32 = (sbad != 0);
    if (t == 0) *flag = sbad;

    if (t < 18) wgf[t] = ldq(wgate, t, f32);

    if (t < 4) {  // bpp[e][o] = sum_m b2[e][m]*Wout[m][o] + bout[o]
        int e = t >> 1, o = t & 1;
        float acc = ldq(bout, o, f32);
        for (int m = 0; m < 32; ++m)
            acc += ldq(b2, e * 32 + m, f32) * ldq(Wout, m * 2 + o, f32);
        bpp[t] = acc;
    }

    const int e = t >> 7;       // 256 threads -> (e, j)
    const int j = t & 127;
    float p0 = 0.f, p1 = 0.f;
    for (int m = 0; m < 32; ++m) {
        float w = ldq(W2, (e * 128 + j) * 32 + m, f32);
        p0 += w * ldq(Wout, m * 2 + 0, f32);
        p1 += w * ldq(Wout, m * 2 + 1, f32);
    }
    float* dst = wpack + j * 24 + e * 12;
    #pragma unroll
    for (int d = 0; d < 9; ++d)
        dst[d] = ldq(W1, (e * 9 + d) * 128 + j, f32);
    dst[9]  = ldq(b1, e * 128 + j, f32);
    dst[10] = p0;
    dst[11] = p1;
}

// ---------------------------------------------------------------------------
// Main: one thread per token, x PINNED in VGPRs (inline-asm barrier kills
// remat). Dense-both experts; weight indices wave-uniform -> s_load stream.
// Coalesced float2 store. Fused loss via last-block ticket.
// ---------------------------------------------------------------------------
__global__ __launch_bounds__(TPB, 8)
void moe_main(const void* __restrict__ xg,
              const int* __restrict__ flag,
              const float* __restrict__ wgf,
              const float* __restrict__ bpp,
              const float* __restrict__ wpack,
              unsigned int* __restrict__ cnt1,
              unsigned int* __restrict__ done,
              float2* __restrict__ out,
              float* __restrict__ loss_out)
{
    __shared__ unsigned int cblk;
    const int tid = threadIdx.x;
    if (tid == 0) cblk = 0u;
    __syncthreads();

    // x: global -> registers (one-time; HBM at 2% so stride-9 slack is free)
    const bool f32 = (*flag) != 0;
    const int base = blockIdx.x * (TPB * 9) + tid * 9;
    float x[9];
    if (f32) {
        const float* xf = (const float*)xg + base;
        #pragma unroll
        for (int d = 0; d < 9; ++d) x[d] = xf[d];
    } else {
        const unsigned short* xu = (const unsigned short*)xg + base;
        #pragma unroll
        for (int d = 0; d < 9; ++d) x[d] = bf2f(xu[d]);
    }
    // PIN: opaque VGPR definition -- compiler can no longer re-load x in the
    // j-loop (R9: LDS remat @VGPR=12; R11: global remat @VGPR=20).
    #pragma unroll
    for (int d = 0; d < 9; ++d) asm volatile("" : "+v"(x[d]));

    // gating: fp32 fma dot, argmax (tie -> expert 0, stable top_k)
    float l0 = 0.f, l1 = 0.f;
    #pragma unroll
    for (int d = 0; d < 9; ++d) {
        l0 = fmaf(x[d], wgf[d * 2 + 0], l0);
        l1 = fmaf(x[d], wgf[d * 2 + 1], l1);
    }
    const bool e1 = l1 > l0;

    unsigned long long bal = __ballot(e1);
    if ((tid & 63) == 0)
        atomicAdd(&cblk, (unsigned int)__popcll(bal));

    // accumulators pre-seeded with folded bias per expert
    float a00 = bpp[0], a01 = bpp[1], a10 = bpp[2], a11 = bpp[3];

    #pragma unroll 4
    for (int j = 0; j < 128; ++j) {
        const float* wp = wpack + j * 24;   // uniform index -> s_load
        float h0 = wp[9], h1 = wp[21];
        #pragma unroll
        for (int d = 0; d < 9; ++d) {
            h0 = fmaf(x[d], wp[d],      h0);
            h1 = fmaf(x[d], wp[12 + d], h1);
        }
        h0 = fmaxf(h0, 0.f);
        h1 = fmaxf(h1, 0.f);
        a00 = fmaf(h0, wp[10], a00);
        a01 = fmaf(h0, wp[11], a01);
        a10 = fmaf(h1, wp[22], a10);
        a11 = fmaf(h1, wp[23], a11);
    }

    float2 o;
    o.x = e1 ? a10 : a00;
    o.y = e1 ? a11 : a01;
    out[blockIdx.x * TPB + tid] = o;   // coalesced 8B/lane

    // block count -> global; last-finished block computes the loss.
    __syncthreads();
    if (tid == 0) {
        atomicAdd(cnt1, cblk);
        __threadfence();
        unsigned int ticket = atomicAdd(done, 1u);
        if (ticket == (unsigned int)(NBLK - 1)) {
            // gates one-hot 1.0 -> importance == load == counts; cv^2 ddof=1:
            // var=(c0-c1)^2/2, mean=N/2; loss = 0.01*2*cv^2 (~1e-9).
            double c1 = (double)atomicAdd(cnt1, 0u);
            double c0 = (double)NTOK - c1;
            double diff = c0 - c1;
            double mean = (double)NTOK * 0.5;
            double cv2  = (0.5 * diff * diff) / (mean * mean + 1e-10);
            *loss_out = (float)(0.02 * cv2);
        }
    }
}

extern "C" void kernel_launch(void* const* d_in, const int* in_sizes, int n_in,
                              void* d_out, int out_size, void* d_ws, size_t ws_size,
                              hipStream_t stream) {
    const void* num_prop = d_in[0]; // [N,9] fp32
    // d_in[1] = cat_prop (unused)
    const void* w_gate   = d_in[2]; // [9,2]
    const void* W1       = d_in[3]; // [2,9,128]
    const void* b1       = d_in[4]; // [2,128]
    const void* W2       = d_in[5]; // [2,128,32]
    const void* b2       = d_in[6]; // [2,32]
    const void* Wout     = d_in[7]; // [32,2]
    const void* bout     = d_in[8]; // [2]
    // d_in[9] = k (==1)

    char* ws = (char*)d_ws;
    unsigned int* cnt1 = (unsigned int*)ws;          // @0
    unsigned int* done = (unsigned int*)(ws + 4);    // @4
    int* flag          = (int*)(ws + 8);             // @8
    float* bpp         = (float*)(ws + 32);          // 4 f
    float* wgf         = (float*)(ws + 64);          // 18 f
    float* wpack       = (float*)(ws + 192);         // 3072 f (interleaved)

    float*  outf = (float*)d_out;                    // fp32: N*2 + loss
    float2* out2 = (float2*)d_out;

    hipLaunchKernelGGL(prep_kernel, dim3(1), dim3(256), 0, stream,
                       num_prop, w_gate, W1, b1, W2, b2, Wout, bout,
                       cnt1, done, flag, bpp, wgf, wpack);
    hipLaunchKernelGGL(moe_main, dim3(NBLK), dim3(TPB), 0, stream,
                       num_prop, flag, wgf, bpp, wpack, cnt1, done,
                       out2, outf + (size_t)NTOK * 2);
}